// Round 18
// baseline (2096.434 us; speedup 1.0000x reference)
//
#include <hip/hip_runtime.h>
#include <hip/hip_cooperative_groups.h>
namespace cg = cooperative_groups;

// ---------------- problem constants ----------------
#define NN   4096
#define TLEN 200
#define NT   199
#define NW   8                        // spike-bit words per neuron
#define NTP  256                      // padded time dim for u slots
#define TN   ((size_t)NT * NN)        // floats per [t][j] aux buffer
#define TN2  ((size_t)NN * NTP)       // floats per u slot ([i][t] layout)

// fp32 gstim tiling
#define BM 128
#define BT 128
#define BK 32
#define BMP 132
#define BTP 132

#define SLOTPK_A (0 | (4 << 6) | (8 << 12) | (12 << 18))
#define SLOTPK_C (32 | (36 << 6) | (40 << 12) | (44 << 18))

typedef __attribute__((ext_vector_type(8))) short short8;     // 8 bf16 = 4 VGPR
typedef __attribute__((ext_vector_type(16))) float f32x16;    // MFMA acc

// u slot map: k0:0/4 k1:4/4 k2:16/8 k3:8/4 k4:12/4 k5:24/8
// k6:32/4 k7:36/4 k8:40/4 k9:44/4 k10:48/16 ; stim mode0:64..67, mode1:68..71

// ================= gsyn body (verbatim round-17 logic) =================
__device__ void gsyn_body(unsigned char* smem, const float* __restrict__ Wdel,
    const int* __restrict__ delays, const unsigned* __restrict__ Sb,
    float* __restrict__ u, int x, int z, int tid,
    int Slog, int kpack, int prepack, int slotpack) {
  const int XOFF = 24576;
  const int ki = z >> Slog, s = z & ((1 << Slog) - 1);
  const int k = (kpack >> (4 * ki)) & 15;
  const int pre = (prepack >> (4 * ki)) & 15;
  const int slot = ((slotpack >> (6 * ki)) & 63) + s;
  const int NJ = NN >> Slog;
  const int jbase = s * NJ;
  const float* __restrict__ Wk = Wdel + (size_t)k * NN * NN;
  const unsigned* __restrict__ Sp = Sb + (size_t)pre * NW * NN;
  const int* __restrict__ dl = delays + (size_t)k * NN;
  float* __restrict__ uo = u + (size_t)slot * TN2;

  const int i0 = x * 128;
  const int wave = tid >> 6, lane = tid & 63;
  const int m = lane & 31, hb = lane >> 5;
  const int wi = wave >> 1, wt = wave & 1;
  const int bmax = wt ? 3 : 4;                 // skip dead t in [224,256)

  f32x16 acc[2][4];
  #pragma unroll
  for (int a = 0; a < 2; ++a)
    #pragma unroll
    for (int b = 0; b < 4; ++b) acc[a][b] = 0.0f;

  const int rb = tid >> 3, kc = tid & 7;     // W staging: row base, float4 col
  const int kx = tid & 31, tg = tid >> 5;    // X staging: k col, t-group

  for (int j0 = 0; j0 < NJ; j0 += 32) {
    // ---- stage W tile: fp32 global -> 3-way bf16 split -> swizzled LDS ----
    #pragma unroll
    for (int mm = 0; mm < 4; ++mm) {
      const int r = rb + 32 * mm;
      const float4 w4 = *(const float4*)&Wk[(size_t)(i0 + r) * NN + jbase + j0 + kc * 4];
      unsigned h[4], md[4], lo[4];
      const float wv[4] = {w4.x, w4.y, w4.z, w4.w};
      #pragma unroll
      for (int e = 0; e < 4; ++e) {
        const unsigned ub = __float_as_uint(wv[e]);
        h[e] = ub >> 16;
        const float r1 = wv[e] - __uint_as_float(ub & 0xFFFF0000u);
        const unsigned u1 = __float_as_uint(r1);
        md[e] = u1 >> 16;
        const float r2 = r1 - __uint_as_float(u1 & 0xFFFF0000u);
        lo[e] = __float_as_uint(r2) >> 16;     // exact: r2 has <= 8 sig bits
      }
      const unsigned base = (unsigned)((r * 64 + kc * 8) ^ ((r & 7) << 4));
      uint2 p0; p0.x = (h[1] << 16) | h[0];  p0.y = (h[3] << 16) | h[2];
      uint2 p1; p1.x = (md[1] << 16) | md[0]; p1.y = (md[3] << 16) | md[2];
      uint2 p2; p2.x = (lo[1] << 16) | lo[0]; p2.y = (lo[3] << 16) | lo[2];
      *(uint2*)(smem + base)          = p0;
      *(uint2*)(smem + 8192 + base)   = p1;
      *(uint2*)(smem + 16384 + base)  = p2;
    }
    // ---- stage X tile: delayed spike bits -> bf16 {0,1}, swizzled [t][k] ----
    {
      const int j = jbase + j0 + kx;
      const int d = dl[j];
      const int tsrc = tg * 32 - d;
      const int w0 = tsrc >> 5;
      const int sh = tsrc & 31;
      const unsigned blo = (w0 >= 0) ? Sp[(size_t)w0 * NN + j] : 0u;
      const unsigned bhi = (w0 + 1 < NW) ? Sp[(size_t)(w0 + 1) * NN + j] : 0u;
      const unsigned wnd = sh ? ((blo >> sh) | (bhi << (32 - sh))) : blo;
      #pragma unroll
      for (int b = 0; b < 32; ++b) {
        const unsigned short xv = ((wnd >> b) & 1u) ? (unsigned short)0x3F80 : (unsigned short)0;
        const int t = tg * 32 + b;
        *(unsigned short*)(smem + XOFF + ((t * 64 + kx * 2) ^ ((t & 7) << 4))) = xv;
      }
    }
    __syncthreads();
    // ---- MFMA: 2 k16-steps, 2 i-tiles x bmax t-tiles x 3 splits ----
    #pragma unroll
    for (int h2 = 0; h2 < 2; ++h2) {
      const int cb = h2 * 32 + hb * 16;
      short8 bfr[4];
      #pragma unroll
      for (int b = 0; b < 4; ++b) {
        if (b < bmax) {
          const int tr = wt * 128 + b * 32 + m;
          bfr[b] = *(const short8*)(smem + XOFF + ((tr * 64 + cb) ^ ((tr & 7) << 4)));
        }
      }
      #pragma unroll
      for (int a = 0; a < 2; ++a) {
        const int ra = wi * 64 + a * 32 + m;
        const unsigned abase = (unsigned)((ra * 64 + cb) ^ ((ra & 7) << 4));
        const short8 a0 = *(const short8*)(smem + abase);
        const short8 a1 = *(const short8*)(smem + 8192 + abase);
        const short8 a2 = *(const short8*)(smem + 16384 + abase);
        #pragma unroll
        for (int b = 0; b < 4; ++b) {
          if (b < bmax) {
            acc[a][b] = __builtin_amdgcn_mfma_f32_32x32x16_bf16(a0, bfr[b], acc[a][b], 0, 0, 0);
            acc[a][b] = __builtin_amdgcn_mfma_f32_32x32x16_bf16(a1, bfr[b], acc[a][b], 0, 0, 0);
            acc[a][b] = __builtin_amdgcn_mfma_f32_32x32x16_bf16(a2, bfr[b], acc[a][b], 0, 0, 0);
          }
        }
      }
    }
    __syncthreads();
  }
  // ---- store: D col = t = lane&31 (coalesced along t in [i][t] layout) ----
  #pragma unroll
  for (int a = 0; a < 2; ++a)
    #pragma unroll
    for (int b = 0; b < 4; ++b) {
      if (b < bmax) {
        const int tt2 = wt * 128 + b * 32 + m;
        #pragma unroll
        for (int r = 0; r < 16; ++r) {
          const int ii = i0 + wi * 64 + a * 32 + (r & 3) + 8 * (r >> 2) + 4 * hb;
          uo[(size_t)ii * NTP + tt2] = acc[a][b][r];
        }
      }
    }
}

// ================= gstim body (verbatim round-17 logic) =================
__device__ void gstim_body(unsigned char* smem, const float* __restrict__ Wsa,
    const float* __restrict__ Wra, const float* __restrict__ stim,
    float* __restrict__ u, int bx, int by, int zi, int tid) {
  float* Ws = (float*)smem;                 // [BK][BMP]
  float* Xs = (float*)(smem + 16896);       // [BK][BTP]
  const int mode = zi >> 2, s = zi & 3;
  const int slot = 64 + 4 * mode + s;
  const int NJ = NN >> 2;
  const int jbase = s * NJ;
  const float* __restrict__ W = mode ? Wra : Wsa;
  float* __restrict__ uo = u + (size_t)slot * TN2;

  const int i0 = bx * BM;
  const int t0 = by * BT;
  const int rg = tid >> 4, cg = tid & 15;
  float acc[8][8] = {};

  for (int k0 = 0; k0 < NJ; k0 += BK) {
    {
      const int kk4 = tid & 7, r = tid >> 3;
      const int sw = 4 * kk4;
      #pragma unroll
      for (int mq = 0; mq < 4; ++mq) {
        const int rr = r + 32 * mq;
        const float4 w = *(const float4*)&W[(size_t)(i0 + rr) * NN + jbase + k0 + 4 * kk4];
        const int pc = rr ^ sw;
        Ws[(4 * kk4 + 0) * BMP + pc] = w.x; Ws[(4 * kk4 + 1) * BMP + pc] = w.y;
        Ws[(4 * kk4 + 2) * BMP + pc] = w.z; Ws[(4 * kk4 + 3) * BMP + pc] = w.w;
      }
    }
    {
      const int kk = tid >> 3, sb8 = tid & 7;
      const int j = jbase + k0 + kk;
      #pragma unroll
      for (int q = 0; q < 4; ++q) {
        float4 xv;
        float* xp = (float*)&xv;
        #pragma unroll
        for (int e = 0; e < 4; ++e) {
          const int tt = t0 + 16 * sb8 + 4 * q + e;
          float x = 0.0f;
          if (tt < NT) {
            const int tc = tt + 1;
            if (mode == 0) {
              x = stim[(size_t)j * TLEN + tc] - 3.0f;
            } else {
              x = (tc >= 4)
                ? fabsf(stim[(size_t)j * TLEN + tc] - stim[(size_t)j * TLEN + tc - 1]) * 10.0f
                : 0.0f;
            }
          }
          xp[e] = x;
        }
        *(float4*)&Xs[kk * BTP + 16 * sb8 + 4 * q] = xv;
      }
    }
    __syncthreads();
    #pragma unroll
    for (int kk = 0; kk < BK; ++kk) {
      const int wsw = 4 * (kk >> 2);
      const float4 ra = *(const float4*)&Ws[kk * BMP + ((rg * 4) ^ wsw)];
      const float4 rbv = *(const float4*)&Ws[kk * BMP + ((64 + rg * 4) ^ wsw)];
      const float4 ca = *(const float4*)&Xs[kk * BTP + cg * 4];
      const float4 cb = *(const float4*)&Xs[kk * BTP + 64 + cg * 4];
      const float rv[8] = {ra.x, ra.y, ra.z, ra.w, rbv.x, rbv.y, rbv.z, rbv.w};
      const float cv[8] = {ca.x, ca.y, ca.z, ca.w, cb.x, cb.y, cb.z, cb.w};
      #pragma unroll
      for (int a = 0; a < 8; ++a)
        #pragma unroll
        for (int b = 0; b < 8; ++b) acc[a][b] += rv[a] * cv[b];
    }
    __syncthreads();
  }
  #pragma unroll
  for (int a = 0; a < 8; ++a) {
    const int ia = i0 + ((a < 4) ? (rg * 4 + a) : (64 + rg * 4 + (a - 4)));
    #pragma unroll
    for (int bh = 0; bh < 2; ++bh) {
      float4 o;
      o.x = acc[a][bh * 4 + 0]; o.y = acc[a][bh * 4 + 1];
      o.z = acc[a][bh * 4 + 2]; o.w = acc[a][bh * 4 + 3];
      *(float4*)&uo[(size_t)ia * NTP + t0 + bh * 64 + cg * 4] = o;
    }
  }
}

// ================= scan bodies (verbatim round-17 logic, per-j) =================
template<int S>
__device__ __forceinline__ float4 sumS4(const float* __restrict__ u, int slot, int tg, int j) {
  float4 r = {0.f, 0.f, 0.f, 0.f};
  #pragma unroll
  for (int q = 0; q < S; ++q) {
    const float4 a = *(const float4*)&u[(size_t)(slot + q) * TN2 + (size_t)j * NTP + tg];
    r.x += a.x; r.y += a.y; r.z += a.z; r.w += a.w;
  }
  return r;
}
__device__ __forceinline__ float fidx(const float4& v, int q) {
  return q == 0 ? v.x : q == 1 ? v.y : q == 2 ? v.z : v.w;
}
__device__ __forceinline__ void flush_bits(unsigned* sb, int j, int t, unsigned& bits) {
  if ((t & 31) == 31 || t == NT - 1) { sb[(size_t)(t >> 5) * NN + j] = bits; bits = 0; }
}

__device__ void scan_a_body(const float* __restrict__ u, unsigned* __restrict__ Sb,
                            int y, int j) {
  const int base = 64 + 4 * y;
  unsigned* sb = Sb + (size_t)(y ? 3 : 0) * NW * NN;
  float v = 0.f; unsigned bits = 0;
  for (int tg = 0; tg < NT; tg += 4) {
    const float4 in4 = sumS4<4>(u, base, tg, j);
    #pragma unroll
    for (int q = 0; q < 4; ++q) {
      const int t = tg + q;
      if (t < NT) {
        float vn = v * 0.9f + fidx(in4, q);
        unsigned s = vn >= 1.0f;
        v = s ? 0.f : vn;
        bits |= s << (t & 31);
        flush_bits(sb, j, t, bits);
      }
    }
  }
}

__device__ void scan_b_body(const float* __restrict__ u, unsigned* __restrict__ Sb,
                            float* __restrict__ p1s, float* __restrict__ p4s,
                            int sa, int j) {
  const int baseA = sa ? 8 : 0, baseB = sa ? 12 : 4;
  float* ps = sa ? p4s : p1s;
  unsigned* sb = Sb + (size_t)(sa ? 4 : 1) * NW * NN;
  float v = 0.f, pa = 0.f, pb = 0.f; unsigned bits = 0;
  for (int tg = 0; tg < NT; tg += 4) {
    const float4 A4 = sumS4<4>(u, baseA, tg, j);
    const float4 B4 = sumS4<4>(u, baseB, tg, j);
    #pragma unroll
    for (int q = 0; q < 4; ++q) {
      const int t = tg + q;
      if (t < NT) {
        pa = pa * 0.8f + fidx(A4, q);
        float vn = v * 0.9f + pa;
        unsigned s = vn >= 1.0f;
        v = s ? 0.f : vn;
        bits |= s << (t & 31);
        flush_bits(sb, j, t, bits);
        pb = pb * 0.8f + fidx(B4, q);
        ps[(size_t)t * NN + j] = 2.0f * pb;
      }
    }
  }
}

__device__ void scan_c_body(const float* __restrict__ u, unsigned* __restrict__ Sb,
                            const float* __restrict__ p1s, const float* __restrict__ p4s,
                            int sa, int j) {
  const int base = sa ? 24 : 16;
  const float* ps = sa ? p4s : p1s;
  unsigned* sb = Sb + (size_t)(sa ? 5 : 2) * NW * NN;
  float v = 0.f, p = 0.f; unsigned bits = 0;
  for (int tg = 0; tg < NT; tg += 4) {
    const float4 A4 = sumS4<8>(u, base, tg, j);
    float P[4];
    #pragma unroll
    for (int q = 0; q < 4; ++q)
      P[q] = (tg + q < NT) ? ps[(size_t)(tg + q) * NN + j] : 0.0f;
    #pragma unroll
    for (int q = 0; q < 4; ++q) {
      const int t = tg + q;
      if (t < NT) {
        p = p * 0.8f + fidx(A4, q);
        float vn = v * 0.9f + (P[q] - p);
        unsigned s = vn >= 1.0f;
        v = s ? 0.f : vn;
        bits |= s << (t & 31);
        flush_bits(sb, j, t, bits);
      }
    }
  }
}

__device__ void scan_d_body(const float* __restrict__ u, unsigned* __restrict__ Sb,
                            float* __restrict__ p79s, int y, int j) {
  if (y == 0) {
    unsigned* sb = Sb + (size_t)6 * NW * NN;
    float v = 0.f, p6 = 0.f, p8 = 0.f; unsigned bits = 0;
    for (int tg = 0; tg < NT; tg += 4) {
      const float4 A4 = sumS4<4>(u, 32, tg, j);
      const float4 B4 = sumS4<4>(u, 40, tg, j);
      #pragma unroll
      for (int q = 0; q < 4; ++q) {
        const int t = tg + q;
        if (t < NT) {
          p6 = p6 * 0.8f + fidx(A4, q);
          p8 = p8 * 0.8f + fidx(B4, q);
          float vn = v * 0.9f + (p6 + p8);
          unsigned s = vn >= 1.0f;
          v = s ? 0.f : vn;
          bits |= s << (t & 31);
          flush_bits(sb, j, t, bits);
        }
      }
    }
  } else {
    float p7 = 0.f, p9 = 0.f;
    for (int tg = 0; tg < NT; tg += 4) {
      const float4 A4 = sumS4<4>(u, 36, tg, j);
      const float4 B4 = sumS4<4>(u, 44, tg, j);
      #pragma unroll
      for (int q = 0; q < 4; ++q) {
        const int t = tg + q;
        if (t < NT) {
          p7 = p7 * 0.8f + fidx(A4, q);
          p9 = p9 * 0.8f + fidx(B4, q);
          p79s[(size_t)t * NN + j] = 2.0f * p7 + 2.0f * p9;
        }
      }
    }
  }
}

__device__ void scan_e_body(const float* __restrict__ u, unsigned* __restrict__ Sb,
                            const float* __restrict__ p79s, int j) {
  unsigned* sb = Sb + (size_t)7 * NW * NN;
  float v = 0.f, p = 0.f; unsigned bits = 0;
  for (int tg = 0; tg < NT; tg += 4) {
    const float4 A4 = sumS4<16>(u, 48, tg, j);
    float P[4];
    #pragma unroll
    for (int q = 0; q < 4; ++q)
      P[q] = (tg + q < NT) ? p79s[(size_t)(tg + q) * NN + j] : 0.0f;
    #pragma unroll
    for (int q = 0; q < 4; ++q) {
      const int t = tg + q;
      if (t < NT) {
        p = p * 0.8f + fidx(A4, q);
        float vn = v * 0.9f + (P[q] - p);
        unsigned s = vn >= 1.0f;
        v = s ? 0.f : vn;
        bits |= s << (t & 31);
        flush_bits(sb, j, t, bits);
      }
    }
  }
}

// ================= fused cooperative kernel: 512 blocks x 256 threads =================
__global__ __launch_bounds__(256, 2) void mega(
    const float* __restrict__ Wdel, const int* __restrict__ delays,
    unsigned* __restrict__ Sb, float* __restrict__ u,
    const float* __restrict__ Wsa, const float* __restrict__ Wra,
    const float* __restrict__ stim, float* __restrict__ p1s,
    float* __restrict__ p4s, float* __restrict__ p79s) {
  cg::grid_group grid = cg::this_grid();
  __shared__ __align__(16) unsigned char smem[40960];
  const int bid = blockIdx.x, tid = threadIdx.x;
  const int gx = bid & 31, gz = bid >> 5;     // gsyn mapping (32 x, 16 z)

  // P0: gstim  (exact (32,2,8) mapping)
  gstim_body(smem, Wsa, Wra, stim, u, bid & 31, (bid >> 5) & 1, bid >> 6, tid);
  grid.sync();
  // P1: scan_a — 16 j per block (spread across all 512 blocks / 256 CUs)
  if (tid < 16) { const int jj = bid * 16 + tid; scan_a_body(u, Sb, jj >> 12, jj & 4095); }
  grid.sync();
  // P2: gsyn round A
  gsyn_body(smem, Wdel, delays, Sb, u, gx, gz, tid, 2, 0x4310, 0x3300, SLOTPK_A);
  grid.sync();
  // P3: scan_b
  if (tid < 16) { const int jj = bid * 16 + tid; scan_b_body(u, Sb, p1s, p4s, jj >> 12, jj & 4095); }
  grid.sync();
  // P4: gsyn round B
  gsyn_body(smem, Wdel, delays, Sb, u, gx, gz, tid, 3, 0x52, 0x41, 16 | (24 << 6));
  grid.sync();
  // P5: scan_c
  if (tid < 16) { const int jj = bid * 16 + tid; scan_c_body(u, Sb, p1s, p4s, jj >> 12, jj & 4095); }
  grid.sync();
  // P6: gsyn round C
  gsyn_body(smem, Wdel, delays, Sb, u, gx, gz, tid, 2, 0x9876, 0x5522, SLOTPK_C);
  grid.sync();
  // P7: scan_d
  if (tid < 16) { const int jj = bid * 16 + tid; scan_d_body(u, Sb, p79s, jj >> 12, jj & 4095); }
  grid.sync();
  // P8: gsyn round D
  gsyn_body(smem, Wdel, delays, Sb, u, gx, gz, tid, 4, 10, 6, 48);
  grid.sync();
  // P9: scan_e — 8 j per block
  if (tid < 8) { const int jj = bid * 8 + tid; scan_e_body(u, Sb, p79s, jj); }
}

// ================= standalone kernels (fallback path, share bodies) =================
__global__ __launch_bounds__(256, 2) void gsyn_k(const float* __restrict__ Wdel,
    const int* __restrict__ delays, const unsigned* __restrict__ Sb,
    float* __restrict__ u, int Slog, int kpack, int prepack, int slotpack) {
  __shared__ __align__(16) unsigned char smem[40960];
  gsyn_body(smem, Wdel, delays, Sb, u, blockIdx.x, blockIdx.y, threadIdx.x,
            Slog, kpack, prepack, slotpack);
}

__global__ __launch_bounds__(256, 2) void gstim_k(const float* __restrict__ Wsa,
    const float* __restrict__ Wra, const float* __restrict__ stim,
    float* __restrict__ u) {
  __shared__ __align__(16) unsigned char smem[40960];
  gstim_body(smem, Wsa, Wra, stim, u, blockIdx.x, blockIdx.y, blockIdx.z, threadIdx.x);
}

__global__ void scan_a_k(const float* __restrict__ u, unsigned* __restrict__ Sb) {
  scan_a_body(u, Sb, blockIdx.y, blockIdx.x * 64 + threadIdx.x);
}
__global__ void scan_b_k(const float* __restrict__ u, unsigned* __restrict__ Sb,
                         float* __restrict__ p1s, float* __restrict__ p4s) {
  scan_b_body(u, Sb, p1s, p4s, blockIdx.y, blockIdx.x * 64 + threadIdx.x);
}
__global__ void scan_c_k(const float* __restrict__ u, unsigned* __restrict__ Sb,
                         const float* __restrict__ p1s, const float* __restrict__ p4s) {
  scan_c_body(u, Sb, p1s, p4s, blockIdx.y, blockIdx.x * 64 + threadIdx.x);
}
__global__ void scan_d_k(const float* __restrict__ u, unsigned* __restrict__ Sb,
                         float* __restrict__ p79s) {
  scan_d_body(u, Sb, p79s, blockIdx.y, blockIdx.x * 64 + threadIdx.x);
}
__global__ void scan_e_k(const float* __restrict__ u, unsigned* __restrict__ Sb,
                         const float* __restrict__ p79s) {
  scan_e_body(u, Sb, p79s, blockIdx.x * 64 + threadIdx.x);
}

// ================= bit -> float expansion =================
__global__ void expand_k(const unsigned* __restrict__ Sb, float* __restrict__ out) {
  const int j = blockIdx.x * 256 + threadIdx.x;
  const int w = blockIdx.y, li = blockIdx.z;
  unsigned bits = Sb[((size_t)li * NW + w) * NN + j];
  float* o = out + ((size_t)li * NN + j) * NT + w * 32;
  int nb = NT - w * 32; if (nb > 32) nb = 32;
  for (int b = 0; b < nb; ++b) o[b] = (float)((bits >> b) & 1u);
}

// ================= launch =================
extern "C" void kernel_launch(void* const* d_in, const int* in_sizes, int n_in,
                              void* d_out, int out_size, void* d_ws, size_t ws_size,
                              hipStream_t stream) {
  const float* stim   = (const float*)d_in[0];
  const float* Wsa    = (const float*)d_in[1];
  const float* Wra    = (const float*)d_in[2];
  const float* Wdel   = (const float*)d_in[3];
  const int*   delays = (const int*)d_in[4];
  float* out = (float*)d_out;
  float* ws  = (float*)d_ws;

  float* u    = ws;                       // 72 slots of TN2 ([i][256])
  float* p1s  = u + 72 * TN2;
  float* p4s  = p1s + TN;
  float* p79s = p4s + TN;
  unsigned* Sb = (unsigned*)(p79s + TN);  // 8 * NW * NN words
  size_t need = (72 * TN2 + 3 * TN + (size_t)8 * NW * NN) * 4;
  if (ws_size < need) return;

  hipMemsetAsync(Sb, 0, (size_t)8 * NW * NN * sizeof(unsigned), stream);

  // ---- fused cooperative path ----
  void* params[10];
  params[0] = (void*)&Wdel;  params[1] = (void*)&delays; params[2] = (void*)&Sb;
  params[3] = (void*)&u;     params[4] = (void*)&Wsa;    params[5] = (void*)&Wra;
  params[6] = (void*)&stim;  params[7] = (void*)&p1s;    params[8] = (void*)&p4s;
  params[9] = (void*)&p79s;
  hipError_t cerr = hipLaunchCooperativeKernel((const void*)mega, dim3(512), dim3(256),
                                               params, 0, stream);
  if (cerr == hipSuccess) {
    expand_k<<<dim3(16, 7, 8), 256, 0, stream>>>(Sb, out);
    return;
  }
  (void)hipGetLastError();   // clear error state; fall back to round-17 sequence

  // ---- fallback: round-17 launch sequence ----
  const dim3 gmf(NN / 128, 16);
  gstim_k<<<dim3(NN / BM, 2, 8), 256, 0, stream>>>(Wsa, Wra, stim, u);
  scan_a_k<<<dim3(64, 2), 64, 0, stream>>>(u, Sb);
  gsyn_k<<<gmf, 256, 0, stream>>>(Wdel, delays, Sb, u, 2, 0x4310, 0x3300, SLOTPK_A);
  scan_b_k<<<dim3(64, 2), 64, 0, stream>>>(u, Sb, p1s, p4s);
  gsyn_k<<<gmf, 256, 0, stream>>>(Wdel, delays, Sb, u, 3, 0x52, 0x41, 16 | (24 << 6));
  scan_c_k<<<dim3(64, 2), 64, 0, stream>>>(u, Sb, p1s, p4s);
  gsyn_k<<<gmf, 256, 0, stream>>>(Wdel, delays, Sb, u, 2, 0x9876, 0x5522, SLOTPK_C);
  scan_d_k<<<dim3(64, 2), 64, 0, stream>>>(u, Sb, p79s);
  gsyn_k<<<gmf, 256, 0, stream>>>(Wdel, delays, Sb, u, 4, 10, 6, 48);
  scan_e_k<<<dim3(64, 1), 64, 0, stream>>>(u, Sb, p79s);
  expand_k<<<dim3(16, 7, 8), 256, 0, stream>>>(Sb, out);
}

// Round 19
// 797.591 us; speedup vs baseline: 2.6285x; 2.6285x over previous
//
#include <hip/hip_runtime.h>

// ---------------- problem constants ----------------
#define NN   4096
#define TLEN 200
#define NT   199
#define NW   8                        // spike-bit words per neuron
#define NTP  256                      // padded time dim for u slots
#define TN   ((size_t)NT * NN)        // floats per [t][j] aux buffer
#define TN2  ((size_t)NN * NTP)       // floats per u slot ([i][t] layout)

// fp32 gstim tiling
#define BM 128
#define BT 128
#define BK 32
#define BMP 132
#define BTP 132

typedef __attribute__((ext_vector_type(8))) short short8;     // 8 bf16 = 4 VGPR
typedef __attribute__((ext_vector_type(16))) float f32x16;    // MFMA acc

// u slot map: k0:0/4 k1:4/4 k2:16/8 k3:8/4 k4:12/4 k5:24/8
// k6:32/4 k7:36/4 k8:40/4 k9:44/4 k10:48/16 ; stim mode0:64..67, mode1:68..71

// ================= MFMA synapse GEMM (round-13 base + dead-tile skip) =================
// u[slot][i][t] = sum_{j in slice} W[k][i][j] * bit(Sb[pre][j], t - delays[k][j])
// Exact 3-way bf16 truncation split of W. wt=1 waves skip dead t in [224,256).
__global__ __launch_bounds__(256, 2) void gsyn(const float* __restrict__ Wdel,
    const int* __restrict__ delays, const unsigned* __restrict__ Sb,
    float* __restrict__ u, int Slog, int kpack, int prepack, int slotpack) {
  const int z = blockIdx.y;
  const int ki = z >> Slog, s = z & ((1 << Slog) - 1);
  const int k = (kpack >> (4 * ki)) & 15;
  const int pre = (prepack >> (4 * ki)) & 15;
  const int slot = ((slotpack >> (6 * ki)) & 63) + s;
  const int NJ = NN >> Slog;
  const int jbase = s * NJ;
  const float* __restrict__ Wk = Wdel + (size_t)k * NN * NN;
  const unsigned* __restrict__ Sp = Sb + (size_t)pre * NW * NN;
  const int* __restrict__ dl = delays + (size_t)k * NN;
  float* __restrict__ uo = u + (size_t)slot * TN2;

  // LDS: 3 W-split tiles [128 rows][32 k] bf16 (8 KB each) + X tile [256 t][32 k] bf16
  __shared__ __align__(16) unsigned char smem[3 * 8192 + 16384];
  #define XOFF 24576

  const int i0 = blockIdx.x * 128;
  const int tid = threadIdx.x;
  const int wave = tid >> 6, lane = tid & 63;
  const int m = lane & 31, hb = lane >> 5;
  const int wi = wave >> 1, wt = wave & 1;
  const int bmax = wt ? 3 : 4;                 // skip dead t in [224,256)

  f32x16 acc[2][4];
  #pragma unroll
  for (int a = 0; a < 2; ++a)
    #pragma unroll
    for (int b = 0; b < 4; ++b) acc[a][b] = 0.0f;

  const int rb = tid >> 3, kc = tid & 7;     // W staging: row base, float4 col
  const int kx = tid & 31, tg = tid >> 5;    // X staging: k col, t-group

  for (int j0 = 0; j0 < NJ; j0 += 32) {
    // ---- stage W tile: fp32 global -> 3-way bf16 split -> swizzled LDS ----
    #pragma unroll
    for (int mm = 0; mm < 4; ++mm) {
      const int r = rb + 32 * mm;
      const float4 w4 = *(const float4*)&Wk[(size_t)(i0 + r) * NN + jbase + j0 + kc * 4];
      unsigned h[4], md[4], lo[4];
      const float wv[4] = {w4.x, w4.y, w4.z, w4.w};
      #pragma unroll
      for (int e = 0; e < 4; ++e) {
        const unsigned ub = __float_as_uint(wv[e]);
        h[e] = ub >> 16;
        const float r1 = wv[e] - __uint_as_float(ub & 0xFFFF0000u);
        const unsigned u1 = __float_as_uint(r1);
        md[e] = u1 >> 16;
        const float r2 = r1 - __uint_as_float(u1 & 0xFFFF0000u);
        lo[e] = __float_as_uint(r2) >> 16;     // exact: r2 has <= 8 sig bits
      }
      const unsigned base = (unsigned)((r * 64 + kc * 8) ^ ((r & 7) << 4));
      uint2 p0; p0.x = (h[1] << 16) | h[0];  p0.y = (h[3] << 16) | h[2];
      uint2 p1; p1.x = (md[1] << 16) | md[0]; p1.y = (md[3] << 16) | md[2];
      uint2 p2; p2.x = (lo[1] << 16) | lo[0]; p2.y = (lo[3] << 16) | lo[2];
      *(uint2*)(smem + base)          = p0;
      *(uint2*)(smem + 8192 + base)   = p1;
      *(uint2*)(smem + 16384 + base)  = p2;
    }
    // ---- stage X tile: delayed spike bits -> bf16 {0,1}, swizzled [t][k] ----
    {
      const int j = jbase + j0 + kx;
      const int d = dl[j];
      const int tsrc = tg * 32 - d;
      const int w0 = tsrc >> 5;
      const int sh = tsrc & 31;
      const unsigned blo = (w0 >= 0) ? Sp[(size_t)w0 * NN + j] : 0u;
      const unsigned bhi = (w0 + 1 < NW) ? Sp[(size_t)(w0 + 1) * NN + j] : 0u;
      const unsigned wnd = sh ? ((blo >> sh) | (bhi << (32 - sh))) : blo;
      #pragma unroll
      for (int b = 0; b < 32; ++b) {
        const unsigned short xv = ((wnd >> b) & 1u) ? (unsigned short)0x3F80 : (unsigned short)0;
        const int t = tg * 32 + b;
        *(unsigned short*)(smem + XOFF + ((t * 64 + kx * 2) ^ ((t & 7) << 4))) = xv;
      }
    }
    __syncthreads();
    // ---- MFMA: 2 k16-steps, 2 i-tiles x bmax t-tiles x 3 splits ----
    #pragma unroll
    for (int h2 = 0; h2 < 2; ++h2) {
      const int cb = h2 * 32 + hb * 16;
      short8 bfr[4];
      #pragma unroll
      for (int b = 0; b < 4; ++b) {
        if (b < bmax) {
          const int tr = wt * 128 + b * 32 + m;
          bfr[b] = *(const short8*)(smem + XOFF + ((tr * 64 + cb) ^ ((tr & 7) << 4)));
        }
      }
      #pragma unroll
      for (int a = 0; a < 2; ++a) {
        const int ra = wi * 64 + a * 32 + m;
        const unsigned abase = (unsigned)((ra * 64 + cb) ^ ((ra & 7) << 4));
        const short8 a0 = *(const short8*)(smem + abase);
        const short8 a1 = *(const short8*)(smem + 8192 + abase);
        const short8 a2 = *(const short8*)(smem + 16384 + abase);
        #pragma unroll
        for (int b = 0; b < 4; ++b) {
          if (b < bmax) {
            acc[a][b] = __builtin_amdgcn_mfma_f32_32x32x16_bf16(a0, bfr[b], acc[a][b], 0, 0, 0);
            acc[a][b] = __builtin_amdgcn_mfma_f32_32x32x16_bf16(a1, bfr[b], acc[a][b], 0, 0, 0);
            acc[a][b] = __builtin_amdgcn_mfma_f32_32x32x16_bf16(a2, bfr[b], acc[a][b], 0, 0, 0);
          }
        }
      }
    }
    __syncthreads();
  }
  // ---- store: D col = t = lane&31 (coalesced along t in [i][t] layout) ----
  #pragma unroll
  for (int a = 0; a < 2; ++a)
    #pragma unroll
    for (int b = 0; b < 4; ++b) {
      if (b < bmax) {
        const int tt2 = wt * 128 + b * 32 + m;
        #pragma unroll
        for (int r = 0; r < 16; ++r) {
          const int ii = i0 + wi * 64 + a * 32 + (r & 3) + 8 * (r >> 2) + 4 * hb;
          uo[(size_t)ii * NTP + tt2] = acc[a][b][r];
        }
      }
    }
  #undef XOFF
}

// ================= stimulus GEMM (fp32 VALU; [i][t] stores) =================
__global__ __launch_bounds__(256, 2) void gstim(const float* __restrict__ Wsa,
    const float* __restrict__ Wra, const float* __restrict__ stim,
    float* __restrict__ u) {
  const int zi = blockIdx.z;            // 0..7
  const int mode = zi >> 2, s = zi & 3;
  const int slot = 64 + 4 * mode + s;
  const int NJ = NN >> 2;
  const int jbase = s * NJ;
  const float* __restrict__ W = mode ? Wra : Wsa;
  float* __restrict__ uo = u + (size_t)slot * TN2;

  __shared__ float Ws[BK][BMP];
  __shared__ float Xs[BK][BTP];
  const int i0 = blockIdx.x * BM;
  const int t0 = blockIdx.y * BT;
  const int tid = threadIdx.x;
  const int rg = tid >> 4, cg = tid & 15;
  float acc[8][8] = {};

  for (int k0 = 0; k0 < NJ; k0 += BK) {
    {
      const int kk4 = tid & 7, r = tid >> 3;
      const int sw = 4 * kk4;
      #pragma unroll
      for (int mq = 0; mq < 4; ++mq) {
        const int rr = r + 32 * mq;
        const float4 w = *(const float4*)&W[(size_t)(i0 + rr) * NN + jbase + k0 + 4 * kk4];
        const int pc = rr ^ sw;
        Ws[4 * kk4 + 0][pc] = w.x; Ws[4 * kk4 + 1][pc] = w.y;
        Ws[4 * kk4 + 2][pc] = w.z; Ws[4 * kk4 + 3][pc] = w.w;
      }
    }
    {
      const int kk = tid >> 3, sb8 = tid & 7;
      const int j = jbase + k0 + kk;
      #pragma unroll
      for (int q = 0; q < 4; ++q) {
        float4 xv;
        float* xp = (float*)&xv;
        #pragma unroll
        for (int e = 0; e < 4; ++e) {
          const int tt = t0 + 16 * sb8 + 4 * q + e;
          float x = 0.0f;
          if (tt < NT) {
            const int tc = tt + 1;
            if (mode == 0) {
              x = stim[(size_t)j * TLEN + tc] - 3.0f;
            } else {
              x = (tc >= 4)
                ? fabsf(stim[(size_t)j * TLEN + tc] - stim[(size_t)j * TLEN + tc - 1]) * 10.0f
                : 0.0f;
            }
          }
          xp[e] = x;
        }
        *(float4*)&Xs[kk][16 * sb8 + 4 * q] = xv;
      }
    }
    __syncthreads();
    #pragma unroll
    for (int kk = 0; kk < BK; ++kk) {
      const int wsw = 4 * (kk >> 2);
      const float4 ra = *(const float4*)&Ws[kk][(rg * 4) ^ wsw];
      const float4 rbv = *(const float4*)&Ws[kk][(64 + rg * 4) ^ wsw];
      const float4 ca = *(const float4*)&Xs[kk][cg * 4];
      const float4 cb = *(const float4*)&Xs[kk][64 + cg * 4];
      const float rv[8] = {ra.x, ra.y, ra.z, ra.w, rbv.x, rbv.y, rbv.z, rbv.w};
      const float cv[8] = {ca.x, ca.y, ca.z, ca.w, cb.x, cb.y, cb.z, cb.w};
      #pragma unroll
      for (int a = 0; a < 8; ++a)
        #pragma unroll
        for (int b = 0; b < 8; ++b) acc[a][b] += rv[a] * cv[b];
    }
    __syncthreads();
  }
  #pragma unroll
  for (int a = 0; a < 8; ++a) {
    const int ia = i0 + ((a < 4) ? (rg * 4 + a) : (64 + rg * 4 + (a - 4)));
    #pragma unroll
    for (int bh = 0; bh < 2; ++bh) {
      float4 o;
      o.x = acc[a][bh * 4 + 0]; o.y = acc[a][bh * 4 + 1];
      o.z = acc[a][bh * 4 + 2]; o.w = acc[a][bh * 4 + 3];
      *(float4*)&uo[(size_t)ia * NTP + t0 + bh * 64 + cg * 4] = o;
    }
  }
}

// ================= scans: 64-thread blocks spread over 64+ CUs; float4 u-loads =================
template<int S>
__device__ __forceinline__ float4 sumS4(const float* __restrict__ u, int slot, int tg, int j) {
  float4 r = {0.f, 0.f, 0.f, 0.f};
  #pragma unroll
  for (int q = 0; q < S; ++q) {
    const float4 a = *(const float4*)&u[(size_t)(slot + q) * TN2 + (size_t)j * NTP + tg];
    r.x += a.x; r.y += a.y; r.z += a.z; r.w += a.w;
  }
  return r;
}
__device__ __forceinline__ float fidx(const float4& v, int q) {
  return q == 0 ? v.x : q == 1 ? v.y : q == 2 ? v.z : v.w;
}

__device__ __forceinline__ void flush_bits(unsigned* sb, int j, int t, unsigned& bits) {
  if ((t & 31) == 31 || t == NT - 1) { sb[(size_t)(t >> 5) * NN + j] = bits; bits = 0; }
}

__global__ void scan_a(const float* __restrict__ u, unsigned* __restrict__ Sb) {
  const int j = blockIdx.x * 64 + threadIdx.x;
  const int base = 64 + 4 * blockIdx.y;
  unsigned* sb = Sb + (size_t)(blockIdx.y ? 3 : 0) * NW * NN;
  float v = 0.f; unsigned bits = 0;
  for (int tg = 0; tg < NT; tg += 4) {
    const float4 in4 = sumS4<4>(u, base, tg, j);
    #pragma unroll
    for (int q = 0; q < 4; ++q) {
      const int t = tg + q;
      if (t < NT) {
        float vn = v * 0.9f + fidx(in4, q);
        unsigned s = vn >= 1.0f;
        v = s ? 0.f : vn;
        bits |= s << (t & 31);
        flush_bits(sb, j, t, bits);
      }
    }
  }
}

__global__ void scan_b(const float* __restrict__ u, unsigned* __restrict__ Sb,
                       float* __restrict__ p1s, float* __restrict__ p4s) {
  const int j = blockIdx.x * 64 + threadIdx.x;
  const int sa = blockIdx.y;
  const int baseA = sa ? 8 : 0, baseB = sa ? 12 : 4;
  float* ps = sa ? p4s : p1s;
  unsigned* sb = Sb + (size_t)(sa ? 4 : 1) * NW * NN;
  float v = 0.f, pa = 0.f, pb = 0.f; unsigned bits = 0;
  for (int tg = 0; tg < NT; tg += 4) {
    const float4 A4 = sumS4<4>(u, baseA, tg, j);
    const float4 B4 = sumS4<4>(u, baseB, tg, j);
    #pragma unroll
    for (int q = 0; q < 4; ++q) {
      const int t = tg + q;
      if (t < NT) {
        pa = pa * 0.8f + fidx(A4, q);
        float vn = v * 0.9f + pa;
        unsigned s = vn >= 1.0f;
        v = s ? 0.f : vn;
        bits |= s << (t & 31);
        flush_bits(sb, j, t, bits);
        pb = pb * 0.8f + fidx(B4, q);
        ps[(size_t)t * NN + j] = 2.0f * pb;
      }
    }
  }
}

__global__ void scan_c(const float* __restrict__ u, unsigned* __restrict__ Sb,
                       const float* __restrict__ p1s, const float* __restrict__ p4s) {
  const int j = blockIdx.x * 64 + threadIdx.x;
  const int sa = blockIdx.y;
  const int base = sa ? 24 : 16;
  const float* ps = sa ? p4s : p1s;
  unsigned* sb = Sb + (size_t)(sa ? 5 : 2) * NW * NN;
  float v = 0.f, p = 0.f; unsigned bits = 0;
  for (int tg = 0; tg < NT; tg += 4) {
    const float4 A4 = sumS4<8>(u, base, tg, j);
    float P[4];
    #pragma unroll
    for (int q = 0; q < 4; ++q)
      P[q] = (tg + q < NT) ? ps[(size_t)(tg + q) * NN + j] : 0.0f;
    #pragma unroll
    for (int q = 0; q < 4; ++q) {
      const int t = tg + q;
      if (t < NT) {
        p = p * 0.8f + fidx(A4, q);
        float vn = v * 0.9f + (P[q] - p);
        unsigned s = vn >= 1.0f;
        v = s ? 0.f : vn;
        bits |= s << (t & 31);
        flush_bits(sb, j, t, bits);
      }
    }
  }
}

__global__ void scan_d(const float* __restrict__ u, unsigned* __restrict__ Sb,
                       float* __restrict__ p79s) {
  const int j = blockIdx.x * 64 + threadIdx.x;
  if (blockIdx.y == 0) {
    unsigned* sb = Sb + (size_t)6 * NW * NN;
    float v = 0.f, p6 = 0.f, p8 = 0.f; unsigned bits = 0;
    for (int tg = 0; tg < NT; tg += 4) {
      const float4 A4 = sumS4<4>(u, 32, tg, j);
      const float4 B4 = sumS4<4>(u, 40, tg, j);
      #pragma unroll
      for (int q = 0; q < 4; ++q) {
        const int t = tg + q;
        if (t < NT) {
          p6 = p6 * 0.8f + fidx(A4, q);
          p8 = p8 * 0.8f + fidx(B4, q);
          float vn = v * 0.9f + (p6 + p8);
          unsigned s = vn >= 1.0f;
          v = s ? 0.f : vn;
          bits |= s << (t & 31);
          flush_bits(sb, j, t, bits);
        }
      }
    }
  } else {
    float p7 = 0.f, p9 = 0.f;
    for (int tg = 0; tg < NT; tg += 4) {
      const float4 A4 = sumS4<4>(u, 36, tg, j);
      const float4 B4 = sumS4<4>(u, 44, tg, j);
      #pragma unroll
      for (int q = 0; q < 4; ++q) {
        const int t = tg + q;
        if (t < NT) {
          p7 = p7 * 0.8f + fidx(A4, q);
          p9 = p9 * 0.8f + fidx(B4, q);
          p79s[(size_t)t * NN + j] = 2.0f * p7 + 2.0f * p9;
        }
      }
    }
  }
}

__global__ void scan_e(const float* __restrict__ u, unsigned* __restrict__ Sb,
                       const float* __restrict__ p79s) {
  const int j = blockIdx.x * 64 + threadIdx.x;
  unsigned* sb = Sb + (size_t)7 * NW * NN;
  float v = 0.f, p = 0.f; unsigned bits = 0;
  for (int tg = 0; tg < NT; tg += 4) {
    const float4 A4 = sumS4<16>(u, 48, tg, j);
    float P[4];
    #pragma unroll
    for (int q = 0; q < 4; ++q)
      P[q] = (tg + q < NT) ? p79s[(size_t)(tg + q) * NN + j] : 0.0f;
    #pragma unroll
    for (int q = 0; q < 4; ++q) {
      const int t = tg + q;
      if (t < NT) {
        p = p * 0.8f + fidx(A4, q);
        float vn = v * 0.9f + (P[q] - p);
        unsigned s = vn >= 1.0f;
        v = s ? 0.f : vn;
        bits |= s << (t & 31);
        flush_bits(sb, j, t, bits);
      }
    }
  }
}

// ================= bit -> float expansion =================
__global__ void expand_k(const unsigned* __restrict__ Sb, float* __restrict__ out) {
  const int j = blockIdx.x * 256 + threadIdx.x;
  const int w = blockIdx.y, li = blockIdx.z;
  unsigned bits = Sb[((size_t)li * NW + w) * NN + j];
  float* o = out + ((size_t)li * NN + j) * NT + w * 32;
  int nb = NT - w * 32; if (nb > 32) nb = 32;
  for (int b = 0; b < nb; ++b) o[b] = (float)((bits >> b) & 1u);
}

// ================= launch =================
extern "C" void kernel_launch(void* const* d_in, const int* in_sizes, int n_in,
                              void* d_out, int out_size, void* d_ws, size_t ws_size,
                              hipStream_t stream) {
  const float* stim   = (const float*)d_in[0];
  const float* Wsa    = (const float*)d_in[1];
  const float* Wra    = (const float*)d_in[2];
  const float* Wdel   = (const float*)d_in[3];
  const int*   delays = (const int*)d_in[4];
  float* out = (float*)d_out;
  float* ws  = (float*)d_ws;

  float* u    = ws;                       // 72 slots of TN2 ([i][256])
  float* p1s  = u + 72 * TN2;
  float* p4s  = p1s + TN;
  float* p79s = p4s + TN;
  unsigned* Sb = (unsigned*)(p79s + TN);  // 8 * NW * NN words
  size_t need = (72 * TN2 + 3 * TN + (size_t)8 * NW * NN) * 4;
  if (ws_size < need) return;

  hipMemsetAsync(Sb, 0, (size_t)8 * NW * NN * sizeof(unsigned), stream);

  const dim3 gmf(NN / 128, 16);           // 32 x 16 = 512 blocks (2/CU)
  gstim<<<dim3(NN / BM, 2, 8), 256, 0, stream>>>(Wsa, Wra, stim, u);
  scan_a<<<dim3(64, 2), 64, 0, stream>>>(u, Sb);

  // round A: syn {0,1,3,4}, pre {0,0,3,3}, S=4, slots {0,4,8,12}
  gsyn<<<gmf, 256, 0, stream>>>(Wdel, delays, Sb, u, 2, 0x4310, 0x3300,
                                0 | (4 << 6) | (8 << 12) | (12 << 18));
  scan_b<<<dim3(64, 2), 64, 0, stream>>>(u, Sb, p1s, p4s);

  // round B: syn {2,5}, pre {1,4}, S=8, slots {16,24}
  gsyn<<<gmf, 256, 0, stream>>>(Wdel, delays, Sb, u, 3, 0x52, 0x41, 16 | (24 << 6));
  scan_c<<<dim3(64, 2), 64, 0, stream>>>(u, Sb, p1s, p4s);

  // round C: syn {6,7,8,9}, pre {2,2,5,5}, S=4, slots {32,36,40,44}
  gsyn<<<gmf, 256, 0, stream>>>(Wdel, delays, Sb, u, 2, 0x9876, 0x5522,
                                32 | (36 << 6) | (40 << 12) | (44 << 18));
  scan_d<<<dim3(64, 2), 64, 0, stream>>>(u, Sb, p79s);

  // round D: syn {10}, pre {6}, S=16, slot 48
  gsyn<<<gmf, 256, 0, stream>>>(Wdel, delays, Sb, u, 4, 10, 6, 48);
  scan_e<<<dim3(64, 1), 64, 0, stream>>>(u, Sb, p79s);

  expand_k<<<dim3(16, 7, 8), 256, 0, stream>>>(Sb, out);
}